// Round 3
// baseline (1042.739 us; speedup 1.0000x reference)
//
#include <hip/hip_runtime.h>

#define N_NODES 100000
#define N_EDGES 1600000
#define NFEAT   128
#define HID     128
#define NG      256
#define NCLS    8

// ---------------- CSR build ----------------

__global__ void zero_int_kernel(int* __restrict__ p, int n) {
    int i = blockIdx.x * 256 + threadIdx.x;
    if (i < n) p[i] = 0;
}

__global__ void count_deg_kernel(const int* __restrict__ dst, int* __restrict__ deg, int e) {
    int i = blockIdx.x * 256 + threadIdx.x;
    if (i < e) atomicAdd(&deg[dst[i]], 1);
}

// inclusive scan of each 256-tile; tile totals to bsums
__global__ void scan1_kernel(const int* __restrict__ deg, int* __restrict__ tmp,
                             int* __restrict__ bsums, int n) {
    __shared__ int s[256];
    int t = threadIdx.x;
    int i = blockIdx.x * 256 + t;
    int v = (i < n) ? deg[i] : 0;
    s[t] = v;
    __syncthreads();
    for (int o = 1; o < 256; o <<= 1) {
        int a = (t >= o) ? s[t - o] : 0;
        __syncthreads();
        s[t] += a;
        __syncthreads();
    }
    if (i < n) tmp[i] = s[t];
    if (t == 255) bsums[blockIdx.x] = s[t];
}

// exclusive scan of block sums (single block, nb <= 512)
__global__ void scan2_kernel(int* __restrict__ bsums, int nb) {
    __shared__ int s[512];
    int t = threadIdx.x;
    int v = (t < nb) ? bsums[t] : 0;
    s[t] = v;
    __syncthreads();
    for (int o = 1; o < 512; o <<= 1) {
        int a = (t >= o) ? s[t - o] : 0;
        __syncthreads();
        s[t] += a;
        __syncthreads();
    }
    if (t < nb) bsums[t] = s[t] - v;   // exclusive
}

// row_ptr/cursor from scan, plus per-node norm scalars (folded node_scalars)
__global__ void scan3_kernel(const int* __restrict__ tmp, const int* __restrict__ bsums,
                             const int* __restrict__ deg, int* __restrict__ row_ptr,
                             int* __restrict__ cursor, float* __restrict__ dinv,
                             float* __restrict__ deg_inv, int n) {
    int b = blockIdx.x;
    int i = b * 256 + threadIdx.x;
    if (i < n) {
        int g  = tmp[i] + bsums[b];   // inclusive global
        int d  = deg[i];
        int rp = g - d;               // exclusive
        row_ptr[i] = rp;
        cursor[i]  = rp;
        float df = (float)d + 1.0f;   // deg = in-degree + 1 (self loop)
        dinv[i]    = rsqrtf(df);
        deg_inv[i] = 1.0f / df;
        if (i == n - 1) row_ptr[n] = g;
    }
}

__global__ void fill_edges_kernel(const int* __restrict__ src, const int* __restrict__ dst,
                                  const float* __restrict__ dinv, int* __restrict__ cursor,
                                  int* __restrict__ col, float* __restrict__ nrm, int e) {
    int i = blockIdx.x * 256 + threadIdx.x;
    if (i < e) {
        int s = src[i], d = dst[i];
        int pos = atomicAdd(&cursor[d], 1);
        col[pos] = s;
        nrm[pos] = dinv[s] * dinv[d];
    }
}

// ---------------- fused layer: out = relu((agg(in)) @ W + b) ----------------
// Block = 1024 threads (16 waves) owns 64 nodes.
// Phase 1: wave w aggregates nodes w*4..w*4+3 into LDS (identical math to the
//          old spmm_kernel: acc = deg_inv*in[node] + sum nrm*in[col]).
// Phase 2: 64x128 LDS tile times W (128x128, L1/L2-resident), thread tile
//          2 rows x 4 cols, bias + relu, coalesced float4 store.
// Occupancy: 32 KiB LDS + 16 waves -> 2 blocks/CU = 32 waves/CU; inter-block
// overlap hides per-block degree-imbalance at the barrier.
__global__ __launch_bounds__(1024) void agg_gemm_relu_kernel(
        const float* __restrict__ in, float* __restrict__ out,
        const int* __restrict__ row_ptr, const int* __restrict__ col,
        const float* __restrict__ nrm, const float* __restrict__ deg_inv,
        const float* __restrict__ W, const float* __restrict__ bias) {
    __shared__ float Yl[64 * 128];
    const int tid  = threadIdx.x;
    const int wave = tid >> 6;          // 0..15
    const int lane = tid & 63;
    const int row0 = blockIdx.x * 64;

    const float2* inp = (const float2*)in;
#pragma unroll
    for (int i = 0; i < 4; ++i) {
        int r    = wave * 4 + i;        // 0..63
        int node = row0 + r;
        float2 acc = make_float2(0.f, 0.f);
        if (node < N_NODES) {
            float di  = deg_inv[node];
            float2 xv = inp[(size_t)node * 64 + lane];
            acc.x = di * xv.x;
            acc.y = di * xv.y;
            int e  = row_ptr[node];
            int e1 = row_ptr[node + 1];
            for (; e + 1 < e1; e += 2) {
                int   c0 = col[e],  c1 = col[e + 1];
                float w0 = nrm[e],  w1 = nrm[e + 1];
                float2 v0 = inp[(size_t)c0 * 64 + lane];
                float2 v1 = inp[(size_t)c1 * 64 + lane];
                acc.x += w0 * v0.x; acc.y += w0 * v0.y;
                acc.x += w1 * v1.x; acc.y += w1 * v1.y;
            }
            if (e < e1) {
                int   c = col[e];
                float w = nrm[e];
                float2 v = inp[(size_t)c * 64 + lane];
                acc.x += w * v.x; acc.y += w * v.y;
            }
        }
        ((float2*)Yl)[r * 64 + lane] = acc;
    }
    __syncthreads();

    const int jg = (tid & 31) << 2;     // 4 consecutive output cols
    const int rg = (tid >> 5) << 1;     // 2 rows, 0..62

    float acc[2][4];
#pragma unroll
    for (int r = 0; r < 2; ++r)
#pragma unroll
        for (int j = 0; j < 4; ++j) acc[r][j] = 0.f;

#pragma unroll 4
    for (int k0 = 0; k0 < 128; k0 += 4) {
        float4 w0 = *(const float4*)&W[(k0 + 0) * 128 + jg];
        float4 w1 = *(const float4*)&W[(k0 + 1) * 128 + jg];
        float4 w2 = *(const float4*)&W[(k0 + 2) * 128 + jg];
        float4 w3 = *(const float4*)&W[(k0 + 3) * 128 + jg];
#pragma unroll
        for (int r = 0; r < 2; ++r) {
            float4 y = *(const float4*)&Yl[(rg + r) * 128 + k0];
            acc[r][0] += y.x * w0.x + y.y * w1.x + y.z * w2.x + y.w * w3.x;
            acc[r][1] += y.x * w0.y + y.y * w1.y + y.z * w2.y + y.w * w3.y;
            acc[r][2] += y.x * w0.z + y.y * w1.z + y.z * w2.z + y.w * w3.z;
            acc[r][3] += y.x * w0.w + y.y * w1.w + y.z * w2.w + y.w * w3.w;
        }
    }

    float4 b4 = *(const float4*)&bias[jg];
#pragma unroll
    for (int r = 0; r < 2; ++r) {
        int gr = row0 + rg + r;
        if (gr < N_NODES) {
            float4 o;
            o.x = fmaxf(acc[r][0] + b4.x, 0.f);
            o.y = fmaxf(acc[r][1] + b4.y, 0.f);
            o.z = fmaxf(acc[r][2] + b4.z, 0.f);
            o.w = fmaxf(acc[r][3] + b4.w, 0.f);
            *(float4*)&out[(size_t)gr * 128 + jg] = o;
        }
    }
}

// ---------------- mean pool over sorted batch ids ----------------
// 512 threads: 4 node-strides x 128 features, LDS reduce at the end.
__global__ __launch_bounds__(512) void pool_kernel(const float* __restrict__ H,
                                                   const int* __restrict__ batch,
                                                   float* __restrict__ pooled) {
    __shared__ float red[4][128];
    int g = blockIdx.x;
    int t = threadIdx.x;
    int f = t & 127;
    int s = t >> 7;                     // 0..3

    // lower_bound(batch, g) and lower_bound(batch, g+1)
    int lo = 0, hi = N_NODES;
    while (lo < hi) { int mid = (lo + hi) >> 1; if (batch[mid] < g) lo = mid + 1; else hi = mid; }
    int start = lo;
    lo = start; hi = N_NODES;
    while (lo < hi) { int mid = (lo + hi) >> 1; if (batch[mid] < g + 1) lo = mid + 1; else hi = mid; }
    int end = lo;

    float acc = 0.f;
    for (int n = start + s; n < end; n += 4) acc += H[(size_t)n * 128 + f];
    red[s][f] = acc;
    __syncthreads();
    if (s == 0) {
        float v   = (red[0][f] + red[1][f]) + (red[2][f] + red[3][f]);
        float cnt = (float)(end - start);
        pooled[g * 128 + f] = v / fmaxf(cnt, 1.0f);
    }
}

// ---------------- classifier head: relu(pooled @ Wc1 + bc1) @ Wc2 + bc2 ----------------
__global__ void classify_kernel(const float* __restrict__ pooled,
                                const float* __restrict__ Wc1, const float* __restrict__ bc1,
                                const float* __restrict__ Wc2, const float* __restrict__ bc2,
                                float* __restrict__ out) {
    __shared__ float p[128];
    __shared__ float z[64];
    int g = blockIdx.x;
    int t = threadIdx.x;   // 64 threads
    p[t]      = pooled[g * 128 + t];
    p[t + 64] = pooled[g * 128 + t + 64];
    __syncthreads();
    float a = bc1[t];
#pragma unroll 4
    for (int k = 0; k < 128; ++k) a += p[k] * Wc1[k * 64 + t];
    z[t] = fmaxf(a, 0.f);
    __syncthreads();
    if (t < 8) {
        float o = bc2[t];
#pragma unroll 8
        for (int j = 0; j < 64; ++j) o += z[j] * Wc2[j * 8 + t];
        out[g * 8 + t] = o;
    }
}

// ---------------- launch ----------------

extern "C" void kernel_launch(void* const* d_in, const int* in_sizes, int n_in,
                              void* d_out, int out_size, void* d_ws, size_t ws_size,
                              hipStream_t stream) {
    const float* x    = (const float*)d_in[0];
    const int*   ei   = (const int*)d_in[1];       // [2][E]
    const int*   bat  = (const int*)d_in[2];
    const float* W1   = (const float*)d_in[3];
    const float* b1   = (const float*)d_in[4];
    const float* W2   = (const float*)d_in[5];
    const float* b2   = (const float*)d_in[6];
    const float* W3   = (const float*)d_in[7];
    const float* b3   = (const float*)d_in[8];
    const float* Wc1  = (const float*)d_in[9];
    const float* bc1  = (const float*)d_in[10];
    const float* Wc2  = (const float*)d_in[11];
    const float* bc2  = (const float*)d_in[12];
    float* out = (float*)d_out;

    const int* src = ei;
    const int* dst = ei + N_EDGES;

    // workspace carve-up (256B aligned)
    char* base = (char*)d_ws;
    size_t off = 0;
    auto alloc = [&](size_t bytes) -> void* {
        void* p = base + off;
        off = (off + bytes + 255) & ~(size_t)255;
        return p;
    };
    int*   deg_int = (int*)  alloc((size_t)N_NODES * 4);
    int*   tmp     = (int*)  alloc((size_t)N_NODES * 4);
    int*   bsums   = (int*)  alloc(512 * 4);
    int*   row_ptr = (int*)  alloc(((size_t)N_NODES + 1) * 4);
    int*   cursor  = (int*)  alloc((size_t)N_NODES * 4);
    float* dinv    = (float*)alloc((size_t)N_NODES * 4);
    float* deg_inv = (float*)alloc((size_t)N_NODES * 4);
    int*   colA    = (int*)  alloc((size_t)N_EDGES * 4);
    float* nrmA    = (float*)alloc((size_t)N_EDGES * 4);
    float* bufA    = (float*)alloc((size_t)N_NODES * 128 * 4);
    float* bufB    = (float*)alloc((size_t)N_NODES * 128 * 4);
    float* pooled  = (float*)alloc((size_t)NG * 128 * 4);
    (void)ws_size; (void)n_in; (void)in_sizes; (void)out_size;

    const int nTilesN  = (N_NODES + 255) / 256;   // 391
    const int nBlocksE = (N_EDGES + 255) / 256;   // 6250

    // CSR build (6 kernels)
    hipLaunchKernelGGL(zero_int_kernel, dim3(nTilesN), dim3(256), 0, stream, deg_int, N_NODES);
    hipLaunchKernelGGL(count_deg_kernel, dim3(nBlocksE), dim3(256), 0, stream, dst, deg_int, N_EDGES);
    hipLaunchKernelGGL(scan1_kernel, dim3(nTilesN), dim3(256), 0, stream, deg_int, tmp, bsums, N_NODES);
    hipLaunchKernelGGL(scan2_kernel, dim3(1), dim3(512), 0, stream, bsums, nTilesN);
    hipLaunchKernelGGL(scan3_kernel, dim3(nTilesN), dim3(256), 0, stream, tmp, bsums, deg_int,
                       row_ptr, cursor, dinv, deg_inv, N_NODES);
    hipLaunchKernelGGL(fill_edges_kernel, dim3(nBlocksE), dim3(256), 0, stream, src, dst, dinv,
                       cursor, colA, nrmA, N_EDGES);

    const int fusedGrid = (N_NODES + 63) / 64;    // 1563

    // fused layers: agg + GEMM + bias + relu
    hipLaunchKernelGGL(agg_gemm_relu_kernel, dim3(fusedGrid), dim3(1024), 0, stream,
                       x,    bufA, row_ptr, colA, nrmA, deg_inv, W1, b1);
    hipLaunchKernelGGL(agg_gemm_relu_kernel, dim3(fusedGrid), dim3(1024), 0, stream,
                       bufA, bufB, row_ptr, colA, nrmA, deg_inv, W2, b2);
    hipLaunchKernelGGL(agg_gemm_relu_kernel, dim3(fusedGrid), dim3(1024), 0, stream,
                       bufB, bufA, row_ptr, colA, nrmA, deg_inv, W3, b3);

    // pool + classifier
    hipLaunchKernelGGL(pool_kernel, dim3(NG), dim3(512), 0, stream, bufA, bat, pooled);
    hipLaunchKernelGGL(classify_kernel, dim3(NG), dim3(64), 0, stream, pooled, Wc1, bc1, Wc2, bc2, out);
}

// Round 6
// 789.589 us; speedup vs baseline: 1.3206x; 1.3206x over previous
//
#include <hip/hip_runtime.h>
#include <hip/hip_bf16.h>

#define N_NODES 100000
#define N_EDGES 1600000
#define NFEAT   128
#define HID     128
#define NG      256
#define NCLS    8

// ---------------- CSR build ----------------

__global__ void zero_int_kernel(int* __restrict__ p, int n) {
    int i = blockIdx.x * 256 + threadIdx.x;
    if (i < n) p[i] = 0;
}

__global__ void count_deg_kernel(const int* __restrict__ dst, int* __restrict__ deg, int e) {
    int i = blockIdx.x * 256 + threadIdx.x;
    if (i < e) atomicAdd(&deg[dst[i]], 1);
}

// inclusive scan of each 256-tile; tile totals to bsums
__global__ void scan1_kernel(const int* __restrict__ deg, int* __restrict__ tmp,
                             int* __restrict__ bsums, int n) {
    __shared__ int s[256];
    int t = threadIdx.x;
    int i = blockIdx.x * 256 + t;
    int v = (i < n) ? deg[i] : 0;
    s[t] = v;
    __syncthreads();
    for (int o = 1; o < 256; o <<= 1) {
        int a = (t >= o) ? s[t - o] : 0;
        __syncthreads();
        s[t] += a;
        __syncthreads();
    }
    if (i < n) tmp[i] = s[t];
    if (t == 255) bsums[blockIdx.x] = s[t];
}

// exclusive scan of block sums (single block, nb <= 512)
__global__ void scan2_kernel(int* __restrict__ bsums, int nb) {
    __shared__ int s[512];
    int t = threadIdx.x;
    int v = (t < nb) ? bsums[t] : 0;
    s[t] = v;
    __syncthreads();
    for (int o = 1; o < 512; o <<= 1) {
        int a = (t >= o) ? s[t - o] : 0;
        __syncthreads();
        s[t] += a;
        __syncthreads();
    }
    if (t < nb) bsums[t] = s[t] - v;   // exclusive
}

// row_ptr/cursor from scan, plus per-node norm scalars
__global__ void scan3_kernel(const int* __restrict__ tmp, const int* __restrict__ bsums,
                             const int* __restrict__ deg, int* __restrict__ row_ptr,
                             int* __restrict__ cursor, float* __restrict__ dinv,
                             float* __restrict__ deg_inv, int n) {
    int b = blockIdx.x;
    int i = b * 256 + threadIdx.x;
    if (i < n) {
        int g  = tmp[i] + bsums[b];   // inclusive global
        int d  = deg[i];
        int rp = g - d;               // exclusive
        row_ptr[i] = rp;
        cursor[i]  = rp;
        float df = (float)d + 1.0f;   // deg = in-degree + 1 (self loop)
        dinv[i]    = rsqrtf(df);
        deg_inv[i] = 1.0f / df;
        if (i == n - 1) row_ptr[n] = g;
    }
}

// packed edge record: .x = src col, .y = float bits of norm
__global__ void fill_edges_kernel(const int* __restrict__ src, const int* __restrict__ dst,
                                  const float* __restrict__ dinv, int* __restrict__ cursor,
                                  uint2* __restrict__ ed, int e) {
    int i = blockIdx.x * 256 + threadIdx.x;
    if (i < e) {
        int s = src[i], d = dst[i];
        int pos = atomicAdd(&cursor[d], 1);
        ed[pos] = make_uint2((unsigned)s, __float_as_uint(dinv[s] * dinv[d]));
    }
}

// ---------------- GEMM: H_bf16 = in_f32 @ W (no bias/relu here) ----------------
// 256 threads, tile 64 rows x 128 cols; in-tile staged in LDS (32 KiB);
// W (64 KiB) from L2. Thread tile: 8 rows x 4 cols. Output written bf16 (RNE).
__device__ __forceinline__ unsigned short f2bf(float f) {
    unsigned u = __float_as_uint(f);
    unsigned r = (u + 0x7fffu + ((u >> 16) & 1u)) >> 16;   // round-nearest-even
    return (unsigned short)r;
}

__global__ __launch_bounds__(256) void gemm_bf16_kernel(const float* __restrict__ in,
                                                        unsigned short* __restrict__ H,
                                                        const float* __restrict__ W) {
    __shared__ float Yl[64 * 128];
    const int tid  = threadIdx.x;
    const int row0 = blockIdx.x * 64;

#pragma unroll
    for (int m = 0; m < 8; ++m) {
        int lin = tid + m * 256;            // 0..2047
        int r   = lin >> 5;                 // 0..63
        int k4  = (lin & 31) << 2;          // 0..124
        int gr  = row0 + r;
        float4 v = make_float4(0.f, 0.f, 0.f, 0.f);
        if (gr < N_NODES) v = *(const float4*)&in[(size_t)gr * 128 + k4];
        *(float4*)&Yl[r * 128 + k4] = v;
    }
    __syncthreads();

    const int jg = (tid & 31) << 2;         // 4 consecutive output cols
    const int rg = (tid >> 5) << 3;         // 8 rows

    float acc[8][4];
#pragma unroll
    for (int r = 0; r < 8; ++r)
#pragma unroll
        for (int j = 0; j < 4; ++j) acc[r][j] = 0.f;

#pragma unroll 2
    for (int k0 = 0; k0 < 128; k0 += 4) {
        float4 w0 = *(const float4*)&W[(k0 + 0) * 128 + jg];
        float4 w1 = *(const float4*)&W[(k0 + 1) * 128 + jg];
        float4 w2 = *(const float4*)&W[(k0 + 2) * 128 + jg];
        float4 w3 = *(const float4*)&W[(k0 + 3) * 128 + jg];
#pragma unroll
        for (int r = 0; r < 8; ++r) {
            float4 y = *(const float4*)&Yl[(rg + r) * 128 + k0];
            acc[r][0] += y.x * w0.x + y.y * w1.x + y.z * w2.x + y.w * w3.x;
            acc[r][1] += y.x * w0.y + y.y * w1.y + y.z * w2.y + y.w * w3.y;
            acc[r][2] += y.x * w0.z + y.y * w1.z + y.z * w2.z + y.w * w3.z;
            acc[r][3] += y.x * w0.w + y.y * w1.w + y.z * w2.w + y.w * w3.w;
        }
    }

#pragma unroll
    for (int r = 0; r < 8; ++r) {
        int gr = row0 + rg + r;
        if (gr < N_NODES) {
            ushort4 o;
            o.x = f2bf(acc[r][0]);
            o.y = f2bf(acc[r][1]);
            o.z = f2bf(acc[r][2]);
            o.w = f2bf(acc[r][3]);
            *(ushort4*)&H[(size_t)gr * 128 + jg] = o;
        }
    }
}

// ---------------- SpMM over bf16 H: out = relu(agg(H) + bias) ----------------
// one wave per node; lane covers 2 consecutive feats (1 uint = 2 bf16).
// f32 accumulation; gather traffic halved vs f32 rows.
__global__ __launch_bounds__(256) void spmm_bias_relu_kernel(
        const unsigned int* __restrict__ H,      // bf16 pairs, row = 64 uints
        float* __restrict__ out,
        const int* __restrict__ row_ptr, const uint2* __restrict__ ed,
        const float* __restrict__ deg_inv, const float* __restrict__ bias) {
    int wave = threadIdx.x >> 6;
    int node = blockIdx.x * 4 + wave;
    int lane = threadIdx.x & 63;
    if (node >= N_NODES) return;

    float di = deg_inv[node];
    unsigned sv = H[(size_t)node * 64 + lane];
    float2 acc;
    acc.x = di * __uint_as_float(sv << 16);
    acc.y = di * __uint_as_float(sv & 0xffff0000u);

    int e  = row_ptr[node];
    int e1 = row_ptr[node + 1];
    for (; e + 1 < e1; e += 2) {
        uint2 d0 = ed[e], d1 = ed[e + 1];
        float w0 = __uint_as_float(d0.y);
        float w1 = __uint_as_float(d1.y);
        unsigned v0 = H[(size_t)d0.x * 64 + lane];
        unsigned v1 = H[(size_t)d1.x * 64 + lane];
        acc.x += w0 * __uint_as_float(v0 << 16);
        acc.y += w0 * __uint_as_float(v0 & 0xffff0000u);
        acc.x += w1 * __uint_as_float(v1 << 16);
        acc.y += w1 * __uint_as_float(v1 & 0xffff0000u);
    }
    if (e < e1) {
        uint2 d0 = ed[e];
        float w0 = __uint_as_float(d0.y);
        unsigned v0 = H[(size_t)d0.x * 64 + lane];
        acc.x += w0 * __uint_as_float(v0 << 16);
        acc.y += w0 * __uint_as_float(v0 & 0xffff0000u);
    }

    float2 b2 = ((const float2*)bias)[lane];
    float2 o;
    o.x = fmaxf(acc.x + b2.x, 0.f);
    o.y = fmaxf(acc.y + b2.y, 0.f);
    ((float2*)out)[(size_t)node * 64 + lane] = o;
}

// ---------------- mean pool over sorted batch ids ----------------
__global__ __launch_bounds__(512) void pool_kernel(const float* __restrict__ H,
                                                   const int* __restrict__ batch,
                                                   float* __restrict__ pooled) {
    __shared__ float red[4][128];
    int g = blockIdx.x;
    int t = threadIdx.x;
    int f = t & 127;
    int s = t >> 7;                     // 0..3

    int lo = 0, hi = N_NODES;
    while (lo < hi) { int mid = (lo + hi) >> 1; if (batch[mid] < g) lo = mid + 1; else hi = mid; }
    int start = lo;
    lo = start; hi = N_NODES;
    while (lo < hi) { int mid = (lo + hi) >> 1; if (batch[mid] < g + 1) lo = mid + 1; else hi = mid; }
    int end = lo;

    float acc = 0.f;
    for (int n = start + s; n < end; n += 4) acc += H[(size_t)n * 128 + f];
    red[s][f] = acc;
    __syncthreads();
    if (s == 0) {
        float v   = (red[0][f] + red[1][f]) + (red[2][f] + red[3][f]);
        float cnt = (float)(end - start);
        pooled[g * 128 + f] = v / fmaxf(cnt, 1.0f);
    }
}

// ---------------- classifier head ----------------
__global__ void classify_kernel(const float* __restrict__ pooled,
                                const float* __restrict__ Wc1, const float* __restrict__ bc1,
                                const float* __restrict__ Wc2, const float* __restrict__ bc2,
                                float* __restrict__ out) {
    __shared__ float p[128];
    __shared__ float z[64];
    int g = blockIdx.x;
    int t = threadIdx.x;   // 64 threads
    p[t]      = pooled[g * 128 + t];
    p[t + 64] = pooled[g * 128 + t + 64];
    __syncthreads();
    float a = bc1[t];
#pragma unroll 4
    for (int k = 0; k < 128; ++k) a += p[k] * Wc1[k * 64 + t];
    z[t] = fmaxf(a, 0.f);
    __syncthreads();
    if (t < 8) {
        float o = bc2[t];
#pragma unroll 8
        for (int j = 0; j < 64; ++j) o += z[j] * Wc2[j * 8 + t];
        out[g * 8 + t] = o;
    }
}

// ---------------- launch ----------------

extern "C" void kernel_launch(void* const* d_in, const int* in_sizes, int n_in,
                              void* d_out, int out_size, void* d_ws, size_t ws_size,
                              hipStream_t stream) {
    const float* x    = (const float*)d_in[0];
    const int*   ei   = (const int*)d_in[1];       // [2][E]
    const int*   bat  = (const int*)d_in[2];
    const float* W1   = (const float*)d_in[3];
    const float* b1   = (const float*)d_in[4];
    const float* W2   = (const float*)d_in[5];
    const float* b2   = (const float*)d_in[6];
    const float* W3   = (const float*)d_in[7];
    const float* b3   = (const float*)d_in[8];
    const float* Wc1  = (const float*)d_in[9];
    const float* bc1  = (const float*)d_in[10];
    const float* Wc2  = (const float*)d_in[11];
    const float* bc2  = (const float*)d_in[12];
    float* out = (float*)d_out;

    const int* src = ei;
    const int* dst = ei + N_EDGES;

    // workspace carve-up (256B aligned)
    char* base = (char*)d_ws;
    size_t off = 0;
    auto alloc = [&](size_t bytes) -> void* {
        void* p = base + off;
        off = (off + bytes + 255) & ~(size_t)255;
        return p;
    };
    int*            deg_int = (int*)           alloc((size_t)N_NODES * 4);
    int*            tmp     = (int*)           alloc((size_t)N_NODES * 4);
    int*            bsums   = (int*)           alloc(512 * 4);
    int*            row_ptr = (int*)           alloc(((size_t)N_NODES + 1) * 4);
    int*            cursor  = (int*)           alloc((size_t)N_NODES * 4);
    float*          dinv    = (float*)         alloc((size_t)N_NODES * 4);
    float*          deg_inv = (float*)         alloc((size_t)N_NODES * 4);
    uint2*          edata   = (uint2*)         alloc((size_t)N_EDGES * 8);
    float*          bufA    = (float*)         alloc((size_t)N_NODES * 128 * 4);
    unsigned short* bufH    = (unsigned short*)alloc((size_t)N_NODES * 128 * 2);
    float*          pooled  = (float*)         alloc((size_t)NG * 128 * 4);
    (void)ws_size; (void)n_in; (void)in_sizes; (void)out_size;

    const int nTilesN  = (N_NODES + 255) / 256;   // 391
    const int nBlocksE = (N_EDGES + 255) / 256;   // 6250

    // CSR build
    hipLaunchKernelGGL(zero_int_kernel, dim3(nTilesN), dim3(256), 0, stream, deg_int, N_NODES);
    hipLaunchKernelGGL(count_deg_kernel, dim3(nBlocksE), dim3(256), 0, stream, dst, deg_int, N_EDGES);
    hipLaunchKernelGGL(scan1_kernel, dim3(nTilesN), dim3(256), 0, stream, deg_int, tmp, bsums, N_NODES);
    hipLaunchKernelGGL(scan2_kernel, dim3(1), dim3(512), 0, stream, bsums, nTilesN);
    hipLaunchKernelGGL(scan3_kernel, dim3(nTilesN), dim3(256), 0, stream, tmp, bsums, deg_int,
                       row_ptr, cursor, dinv, deg_inv, N_NODES);
    hipLaunchKernelGGL(fill_edges_kernel, dim3(nBlocksE), dim3(256), 0, stream, src, dst, dinv,
                       cursor, edata, N_EDGES);

    const int gemmGrid = (N_NODES + 63) / 64;     // 1563
    const int spmmGrid = N_NODES / 4;             // 25000 (exact)

    // layer 1: H = x @ W1 (bf16), out = relu(agg(H) + b1)
    hipLaunchKernelGGL(gemm_bf16_kernel, dim3(gemmGrid), dim3(256), 0, stream, x, bufH, W1);
    hipLaunchKernelGGL(spmm_bias_relu_kernel, dim3(spmmGrid), dim3(256), 0, stream,
                       (const unsigned int*)bufH, bufA, row_ptr, edata, deg_inv, b1);
    // layer 2
    hipLaunchKernelGGL(gemm_bf16_kernel, dim3(gemmGrid), dim3(256), 0, stream, bufA, bufH, W2);
    hipLaunchKernelGGL(spmm_bias_relu_kernel, dim3(spmmGrid), dim3(256), 0, stream,
                       (const unsigned int*)bufH, bufA, row_ptr, edata, deg_inv, b2);
    // layer 3
    hipLaunchKernelGGL(gemm_bf16_kernel, dim3(gemmGrid), dim3(256), 0, stream, bufA, bufH, W3);
    hipLaunchKernelGGL(spmm_bias_relu_kernel, dim3(spmmGrid), dim3(256), 0, stream,
                       (const unsigned int*)bufH, bufA, row_ptr, edata, deg_inv, b3);

    // pool + classifier
    hipLaunchKernelGGL(pool_kernel, dim3(NG), dim3(512), 0, stream, bufA, bat, pooled);
    hipLaunchKernelGGL(classify_kernel, dim3(NG), dim3(64), 0, stream, pooled, Wc1, bc1, Wc2, bc2, out);
}

// Round 9
// 731.404 us; speedup vs baseline: 1.4257x; 1.0796x over previous
//
#include <hip/hip_runtime.h>
#include <hip/hip_bf16.h>

#define N_NODES 100000
#define N_EDGES 1600000
#define NFEAT   128
#define HID     128
#define NG      256
#define NCLS    8

typedef __attribute__((ext_vector_type(8))) short bf16x8;
typedef __attribute__((ext_vector_type(4))) float f32x4;

__device__ __forceinline__ unsigned short f2bf(float f) {
    unsigned u = __float_as_uint(f);
    unsigned r = (u + 0x7fffu + ((u >> 16) & 1u)) >> 16;   // round-nearest-even
    return (unsigned short)r;
}

// ---------------- CSR build ----------------

__global__ void zero_int_kernel(int* __restrict__ p, int n) {
    int i = blockIdx.x * 256 + threadIdx.x;
    if (i < n) p[i] = 0;
}

__global__ void count_deg_kernel(const int* __restrict__ dst, int* __restrict__ deg, int e) {
    int i = blockIdx.x * 256 + threadIdx.x;
    if (i < e) atomicAdd(&deg[dst[i]], 1);
}

// inclusive scan of each 256-tile; tile totals to bsums
__global__ void scan1_kernel(const int* __restrict__ deg, int* __restrict__ tmp,
                             int* __restrict__ bsums, int n) {
    __shared__ int s[256];
    int t = threadIdx.x;
    int i = blockIdx.x * 256 + t;
    int v = (i < n) ? deg[i] : 0;
    s[t] = v;
    __syncthreads();
    for (int o = 1; o < 256; o <<= 1) {
        int a = (t >= o) ? s[t - o] : 0;
        __syncthreads();
        s[t] += a;
        __syncthreads();
    }
    if (i < n) tmp[i] = s[t];
    if (t == 255) bsums[blockIdx.x] = s[t];
}

// exclusive scan of block sums (single block, nb <= 512)
__global__ void scan2_kernel(int* __restrict__ bsums, int nb) {
    __shared__ int s[512];
    int t = threadIdx.x;
    int v = (t < nb) ? bsums[t] : 0;
    s[t] = v;
    __syncthreads();
    for (int o = 1; o < 512; o <<= 1) {
        int a = (t >= o) ? s[t - o] : 0;
        __syncthreads();
        s[t] += a;
        __syncthreads();
    }
    if (t < nb) bsums[t] = s[t] - v;   // exclusive
}

// row_ptr/cursor from scan, plus per-node norm scalars
__global__ void scan3_kernel(const int* __restrict__ tmp, const int* __restrict__ bsums,
                             const int* __restrict__ deg, int* __restrict__ row_ptr,
                             int* __restrict__ cursor, float* __restrict__ dinv,
                             float* __restrict__ deg_inv, int n) {
    int b = blockIdx.x;
    int i = b * 256 + threadIdx.x;
    if (i < n) {
        int g  = tmp[i] + bsums[b];   // inclusive global
        int d  = deg[i];
        int rp = g - d;               // exclusive
        row_ptr[i] = rp;
        cursor[i]  = rp;
        float df = (float)d + 1.0f;   // deg = in-degree + 1 (self loop)
        dinv[i]    = rsqrtf(df);
        deg_inv[i] = 1.0f / df;
        if (i == n - 1) row_ptr[n] = g;
    }
}

// packed edge record: .x = src col, .y = float bits of norm
__global__ void fill_edges_kernel(const int* __restrict__ src, const int* __restrict__ dst,
                                  const float* __restrict__ dinv, int* __restrict__ cursor,
                                  uint2* __restrict__ ed, int e) {
    int i = blockIdx.x * 256 + threadIdx.x;
    if (i < e) {
        int s = src[i], d = dst[i];
        int pos = atomicAdd(&cursor[d], 1);
        ed[pos] = make_uint2((unsigned)s, __float_as_uint(dinv[s] * dinv[d]));
    }
}

// ---------------- W cast+transpose: Wt[n][k] = bf16(W[k][n]) ----------------
// grid = 192 blocks x 256: blocks 0-63 -> W1, 64-127 -> W2, 128-191 -> W3.
__global__ void cast_w_kernel(const float* __restrict__ W1, const float* __restrict__ W2,
                              const float* __restrict__ W3,
                              unsigned short* __restrict__ T1, unsigned short* __restrict__ T2,
                              unsigned short* __restrict__ T3) {
    int b = blockIdx.x;
    const float*    W = (b < 64) ? W1 : ((b < 128) ? W2 : W3);
    unsigned short* T = (b < 64) ? T1 : ((b < 128) ? T2 : T3);
    int i = (b & 63) * 256 + threadIdx.x;    // 0..16383, coalesced read
    int k = i >> 7, n = i & 127;
    T[n * 128 + k] = f2bf(W[i]);             // scattered 2-B writes, 32 KB total
}

// ---------------- MFMA GEMM: H_bf16 = bf16(in_f32) @ Wt_bf16 ----------------
// 256 threads = 4 waves; wave owns 16 output rows x 128 cols; 32 MFMAs/wave.
// A frags direct from global f32 (lanes {r,r+16,r+32,r+48} cover row r's K),
// converted in-register; B frags from Wt[n][k] bf16 (32 KB, L1-resident).
// mfma_f32_16x16x32_bf16: A lane l -> A[l&15][(l>>4)*8 + j]; B lane l ->
// B[(l>>4)*8 + j][l&15]; D lane l -> D[(l>>4)*4 + reg][l&15]  (m89 mapping).
__global__ __launch_bounds__(256) void gemm_mfma_kernel(
        const float* __restrict__ in, unsigned short* __restrict__ H,
        const unsigned short* __restrict__ Wt) {
    const int tid  = threadIdx.x;
    const int wave = tid >> 6;
    const int lane = tid & 63;
    const int r16  = lane & 15;          // A-row / D-col within 16-tile
    const int g    = lane >> 4;          // k-subchunk 0..3
    const int arow = blockIdx.x * 64 + wave * 16 + r16;
    const int arowc = (arow < N_NODES) ? arow : (N_NODES - 1);   // clamp loads

    // A fragments: a[kk] = in[arow][kk*32 + g*8 .. +8) as bf16x8
    bf16x8 a[4];
#pragma unroll
    for (int kk = 0; kk < 4; ++kk) {
        const float* p = &in[(size_t)arowc * 128 + kk * 32 + g * 8];
        float4 lo = *(const float4*)p;
        float4 hi = *(const float4*)(p + 4);
        union { bf16x8 v; unsigned short u[8]; } t;
        t.u[0] = f2bf(lo.x); t.u[1] = f2bf(lo.y); t.u[2] = f2bf(lo.z); t.u[3] = f2bf(lo.w);
        t.u[4] = f2bf(hi.x); t.u[5] = f2bf(hi.y); t.u[6] = f2bf(hi.z); t.u[7] = f2bf(hi.w);
        a[kk] = t.v;
    }

    const bf16x8* Wv = (const bf16x8*)Wt;       // frag idx = n*16 + k/8
    const int orow0 = blockIdx.x * 64 + wave * 16 + g * 4;

#pragma unroll
    for (int ct = 0; ct < 8; ++ct) {
        const int nb = (ct * 16 + r16) * 16 + g;   // B frag base for this col
        f32x4 acc = {0.f, 0.f, 0.f, 0.f};
#pragma unroll
        for (int kk = 0; kk < 4; ++kk)
            acc = __builtin_amdgcn_mfma_f32_16x16x32_bf16(a[kk], Wv[nb + kk * 4], acc, 0, 0, 0);
        const int col = ct * 16 + r16;
#pragma unroll
        for (int i = 0; i < 4; ++i) {
            int gr = orow0 + i;
            if (gr < N_NODES) H[(size_t)gr * 128 + col] = f2bf(acc[i]);
        }
    }
}

// ---------------- SpMM over bf16 H: out = relu(agg(H) + bias) ----------------
// one wave per node; lane covers 2 consecutive feats (1 uint = 2 bf16).
__global__ __launch_bounds__(256) void spmm_bias_relu_kernel(
        const unsigned int* __restrict__ H,      // bf16 pairs, row = 64 uints
        float* __restrict__ out,
        const int* __restrict__ row_ptr, const uint2* __restrict__ ed,
        const float* __restrict__ deg_inv, const float* __restrict__ bias) {
    int wave = threadIdx.x >> 6;
    int node = blockIdx.x * 4 + wave;
    int lane = threadIdx.x & 63;
    if (node >= N_NODES) return;

    float di = deg_inv[node];
    unsigned sv = H[(size_t)node * 64 + lane];
    float2 acc;
    acc.x = di * __uint_as_float(sv << 16);
    acc.y = di * __uint_as_float(sv & 0xffff0000u);

    int e  = row_ptr[node];
    int e1 = row_ptr[node + 1];
    for (; e + 1 < e1; e += 2) {
        uint2 d0 = ed[e], d1 = ed[e + 1];
        float w0 = __uint_as_float(d0.y);
        float w1 = __uint_as_float(d1.y);
        unsigned v0 = H[(size_t)d0.x * 64 + lane];
        unsigned v1 = H[(size_t)d1.x * 64 + lane];
        acc.x += w0 * __uint_as_float(v0 << 16);
        acc.y += w0 * __uint_as_float(v0 & 0xffff0000u);
        acc.x += w1 * __uint_as_float(v1 << 16);
        acc.y += w1 * __uint_as_float(v1 & 0xffff0000u);
    }
    if (e < e1) {
        uint2 d0 = ed[e];
        float w0 = __uint_as_float(d0.y);
        unsigned v0 = H[(size_t)d0.x * 64 + lane];
        acc.x += w0 * __uint_as_float(v0 << 16);
        acc.y += w0 * __uint_as_float(v0 & 0xffff0000u);
    }

    float2 b2 = ((const float2*)bias)[lane];
    float2 o;
    o.x = fmaxf(acc.x + b2.x, 0.f);
    o.y = fmaxf(acc.y + b2.y, 0.f);
    ((float2*)out)[(size_t)node * 64 + lane] = o;
}

// ---------------- mean pool over sorted batch ids ----------------
__global__ __launch_bounds__(512) void pool_kernel(const float* __restrict__ H,
                                                   const int* __restrict__ batch,
                                                   float* __restrict__ pooled) {
    __shared__ float red[4][128];
    int g = blockIdx.x;
    int t = threadIdx.x;
    int f = t & 127;
    int s = t >> 7;                     // 0..3

    int lo = 0, hi = N_NODES;
    while (lo < hi) { int mid = (lo + hi) >> 1; if (batch[mid] < g) lo = mid + 1; else hi = mid; }
    int start = lo;
    lo = start; hi = N_NODES;
    while (lo < hi) { int mid = (lo + hi) >> 1; if (batch[mid] < g + 1) lo = mid + 1; else hi = mid; }
    int end = lo;

    float acc = 0.f;
    for (int n = start + s; n < end; n += 4) acc += H[(size_t)n * 128 + f];
    red[s][f] = acc;
    __syncthreads();
    if (s == 0) {
        float v   = (red[0][f] + red[1][f]) + (red[2][f] + red[3][f]);
        float cnt = (float)(end - start);
        pooled[g * 128 + f] = v / fmaxf(cnt, 1.0f);
    }
}

// ---------------- classifier head ----------------
__global__ void classify_kernel(const float* __restrict__ pooled,
                                const float* __restrict__ Wc1, const float* __restrict__ bc1,
                                const float* __restrict__ Wc2, const float* __restrict__ bc2,
                                float* __restrict__ out) {
    __shared__ float p[128];
    __shared__ float z[64];
    int g = blockIdx.x;
    int t = threadIdx.x;   // 64 threads
    p[t]      = pooled[g * 128 + t];
    p[t + 64] = pooled[g * 128 + t + 64];
    __syncthreads();
    float a = bc1[t];
#pragma unroll 4
    for (int k = 0; k < 128; ++k) a += p[k] * Wc1[k * 64 + t];
    z[t] = fmaxf(a, 0.f);
    __syncthreads();
    if (t < 8) {
        float o = bc2[t];
#pragma unroll 8
        for (int j = 0; j < 64; ++j) o += z[j] * Wc2[j * 8 + t];
        out[g * 8 + t] = o;
    }
}

// ---------------- launch ----------------

extern "C" void kernel_launch(void* const* d_in, const int* in_sizes, int n_in,
                              void* d_out, int out_size, void* d_ws, size_t ws_size,
                              hipStream_t stream) {
    const float* x    = (const float*)d_in[0];
    const int*   ei   = (const int*)d_in[1];       // [2][E]
    const int*   bat  = (const int*)d_in[2];
    const float* W1   = (const float*)d_in[3];
    const float* b1   = (const float*)d_in[4];
    const float* W2   = (const float*)d_in[5];
    const float* b2   = (const float*)d_in[6];
    const float* W3   = (const float*)d_in[7];
    const float* b3   = (const float*)d_in[8];
    const float* Wc1  = (const float*)d_in[9];
    const float* bc1  = (const float*)d_in[10];
    const float* Wc2  = (const float*)d_in[11];
    const float* bc2  = (const float*)d_in[12];
    float* out = (float*)d_out;

    const int* src = ei;
    const int* dst = ei + N_EDGES;

    // workspace carve-up (256B aligned)
    char* base = (char*)d_ws;
    size_t off = 0;
    auto alloc = [&](size_t bytes) -> void* {
        void* p = base + off;
        off = (off + bytes + 255) & ~(size_t)255;
        return p;
    };
    int*            deg_int = (int*)           alloc((size_t)N_NODES * 4);
    int*            tmp     = (int*)           alloc((size_t)N_NODES * 4);
    int*            bsums   = (int*)           alloc(512 * 4);
    int*            row_ptr = (int*)           alloc(((size_t)N_NODES + 1) * 4);
    int*            cursor  = (int*)           alloc((size_t)N_NODES * 4);
    float*          dinv    = (float*)         alloc((size_t)N_NODES * 4);
    float*          deg_inv = (float*)         alloc((size_t)N_NODES * 4);
    uint2*          edata   = (uint2*)         alloc((size_t)N_EDGES * 8);
    float*          bufA    = (float*)         alloc((size_t)N_NODES * 128 * 4);
    unsigned short* bufH    = (unsigned short*)alloc((size_t)N_NODES * 128 * 2);
    float*          pooled  = (float*)         alloc((size_t)NG * 128 * 4);
    unsigned short* Wt1     = (unsigned short*)alloc((size_t)HID * HID * 2);
    unsigned short* Wt2     = (unsigned short*)alloc((size_t)HID * HID * 2);
    unsigned short* Wt3     = (unsigned short*)alloc((size_t)HID * HID * 2);
    (void)ws_size; (void)n_in; (void)in_sizes; (void)out_size;

    const int nTilesN  = (N_NODES + 255) / 256;   // 391
    const int nBlocksE = (N_EDGES + 255) / 256;   // 6250

    // CSR build + W cast (independent; W cast first so it overlaps nothing critical)
    hipLaunchKernelGGL(cast_w_kernel, dim3(192), dim3(256), 0, stream, W1, W2, W3, Wt1, Wt2, Wt3);
    hipLaunchKernelGGL(zero_int_kernel, dim3(nTilesN), dim3(256), 0, stream, deg_int, N_NODES);
    hipLaunchKernelGGL(count_deg_kernel, dim3(nBlocksE), dim3(256), 0, stream, dst, deg_int, N_EDGES);
    hipLaunchKernelGGL(scan1_kernel, dim3(nTilesN), dim3(256), 0, stream, deg_int, tmp, bsums, N_NODES);
    hipLaunchKernelGGL(scan2_kernel, dim3(1), dim3(512), 0, stream, bsums, nTilesN);
    hipLaunchKernelGGL(scan3_kernel, dim3(nTilesN), dim3(256), 0, stream, tmp, bsums, deg_int,
                       row_ptr, cursor, dinv, deg_inv, N_NODES);
    hipLaunchKernelGGL(fill_edges_kernel, dim3(nBlocksE), dim3(256), 0, stream, src, dst, dinv,
                       cursor, edata, N_EDGES);

    const int gemmGrid = (N_NODES + 63) / 64;     // 1563
    const int spmmGrid = N_NODES / 4;             // 25000 (exact)

    // layer 1: H = bf16(x) @ Wt1 (MFMA), out = relu(agg(H) + b1)
    hipLaunchKernelGGL(gemm_mfma_kernel, dim3(gemmGrid), dim3(256), 0, stream, x, bufH, Wt1);
    hipLaunchKernelGGL(spmm_bias_relu_kernel, dim3(spmmGrid), dim3(256), 0, stream,
                       (const unsigned int*)bufH, bufA, row_ptr, edata, deg_inv, b1);
    // layer 2
    hipLaunchKernelGGL(gemm_mfma_kernel, dim3(gemmGrid), dim3(256), 0, stream, bufA, bufH, Wt2);
    hipLaunchKernelGGL(spmm_bias_relu_kernel, dim3(spmmGrid), dim3(256), 0, stream,
                       (const unsigned int*)bufH, bufA, row_ptr, edata, deg_inv, b2);
    // layer 3
    hipLaunchKernelGGL(gemm_mfma_kernel, dim3(gemmGrid), dim3(256), 0, stream, bufA, bufH, Wt3);
    hipLaunchKernelGGL(spmm_bias_relu_kernel, dim3(spmmGrid), dim3(256), 0, stream,
                       (const unsigned int*)bufH, bufA, row_ptr, edata, deg_inv, b3);

    // pool + classifier
    hipLaunchKernelGGL(pool_kernel, dim3(NG), dim3(512), 0, stream, bufA, bat, pooled);
    hipLaunchKernelGGL(classify_kernel, dim3(NG), dim3(64), 0, stream, pooled, Wc1, bc1, Wc2, bc2, out);
}